// Round 7
// baseline (297.874 us; speedup 1.0000x reference)
//
#include <hip/hip_runtime.h>
#include <hip/hip_bf16.h>
#include <stdint.h>

// Problem constants
#define B_    16
#define N_    577
#define C_    768
#define H_    12
#define M_    (B_*N_)     // 9232 rows
#define QKVN  (3*C_)      // 2304
#define NKEEP 403         // int(576*0.7)
#define KROWS (NKEEP+1)   // 404
#define VTLD  640         // vtbuf padded row length
#define PTLD  72          // Ptt row stride (ushorts)

typedef short s16x8 __attribute__((ext_vector_type(8)));
typedef float f32x4 __attribute__((ext_vector_type(4)));

__device__ __forceinline__ unsigned short f2bf(float x){
  unsigned int u = __float_as_uint(x);
  u += 0x7FFF + ((u >> 16) & 1);          // round-to-nearest-even
  return (unsigned short)(u >> 16);
}

// async global->LDS, 16B per lane; lds dest = wave-uniform base + lane*16
__device__ __forceinline__ void gld_lds16(const void* g, void* l){
  __builtin_amdgcn_global_load_lds(
      (const __attribute__((address_space(1))) unsigned int*)g,
      (__attribute__((address_space(3))) unsigned int*)l, 16, 0, 0);
}

// XCD-panel tile mapping: xcd = L&7 owns m-panel [x*9, x*9+9); row-72 tail
// distributed to match round-robin per-XCD block counts exactly (bijective).
template<int NT>
__device__ __forceinline__ void tile_map(int L, int& mt, int& nt){
  constexpr int NB = 73*NT;
  int x = L & 7, j = L >> 3;
  if(j < 9*NT){
    nt = j/9; mt = x*9 + (j - nt*9);       // n-outer: 9 consecutive blocks share B-tile
  } else {
    mt = 72;
    int offt = 0;
    #pragma unroll
    for(int y=0;y<8;y++) if(y<x) offt += ((NB-1-y)>>3) + 1 - 9*NT;  // tail_y
    nt = offt + (j - 9*NT);
  }
}

// ---------------- cast x -> bf16 (vectorized) ----------------
__global__ void k_cvt_x(const float* __restrict__ x, unsigned short* __restrict__ xb){
  int i = blockIdx.x*256 + threadIdx.x;
  float4 v = ((const float4*)x)[i];
  ushort4 o; o.x=f2bf(v.x); o.y=f2bf(v.y); o.z=f2bf(v.z); o.w=f2bf(v.w);
  ((ushort4*)xb)[i] = o;
}

// ------------- transpose+cast weights: out[c][r] = bf16(in[r][c]) -------------
__global__ void k_transpose_cvt(const float* __restrict__ in, unsigned short* __restrict__ out,
                                int R, int CC){
  __shared__ float tile[64][65];
  int r0 = blockIdx.y*64, c0 = blockIdx.x*64;
  int tx = threadIdx.x & 63, ty = threadIdx.x >> 6;
  #pragma unroll
  for(int i=0;i<16;i++){
    int r = ty + i*4;
    tile[r][tx] = in[(size_t)(r0+r)*CC + c0 + tx];
  }
  __syncthreads();
  #pragma unroll
  for(int i=0;i<16;i++){
    int c = ty + i*4;
    out[(size_t)(c0+c)*R + r0 + tx] = f2bf(tile[tx][c]);
  }
}

// ---------------- bf16 MFMA GEMM, 128x64 tile, wave-tile 64x32 (32 AGPR) ----------------
// 2-barrier K-loop (round-5 form). FUSEV: n-tiles >= 1536 write transposed V to vtbuf.
template<int LDC_, bool BF16OUT, bool FUSEV, int NT>
__global__ __launch_bounds__(256) void k_gemm_bt(const unsigned short* __restrict__ A,
                          const unsigned short* __restrict__ Bt,
                          void* __restrict__ Cout,
                          const float* __restrict__ bias, int Mdim,
                          unsigned short* __restrict__ vtbuf){
  __shared__ __align__(16) unsigned short As[128*32];   // 8 KB
  __shared__ __align__(16) unsigned short Bs[64*32];    // 4 KB
  const int t = threadIdx.x;
  const int w = t>>6, l = t&63, lq = l>>4, lr = l&15;
  const int wm = w>>1, wn = w&1;                        // 2x2 waves: 64-row x 32-col
  int mt, nt; tile_map<NT>(blockIdx.x, mt, nt);
  const int m0 = mt*128, n0 = nt*64;
  int rA0 = m0 + (t>>2);       if(rA0 >= Mdim) rA0 = Mdim-1;
  int rA1 = m0 + ((t+256)>>2); if(rA1 >= Mdim) rA1 = Mdim-1;
  const unsigned short* gA0 = A  + (size_t)rA0*768 + (t&3)*8;
  const unsigned short* gA1 = A  + (size_t)rA1*768 + (t&3)*8;
  const unsigned short* gB0 = Bt + (size_t)(n0 + (t>>2))*768 + (t&3)*8;   // t<256 covers 64 rows
  unsigned short* lA0 = As + (size_t)w*512;             // wave-uniform bases
  unsigned short* lA1 = As + 2048 + (size_t)w*512;
  unsigned short* lB0 = Bs + (size_t)w*512;
  f32x4 acc[4][2] = {};
  for(int kt=0; kt<24; ++kt){
    const int ko = kt*32;
    __syncthreads();
    gld_lds16(gA0 + ko, lA0); gld_lds16(gA1 + ko, lA1);
    gld_lds16(gB0 + ko, lB0);
    __syncthreads();
    s16x8 af[4], bfr[2];
    #pragma unroll
    for(int it=0;it<4;it++) af[it]  = *(const s16x8*)&As[(wm*64+it*16+lr)*32 + lq*8];
    #pragma unroll
    for(int jt=0;jt<2;jt++) bfr[jt] = *(const s16x8*)&Bs[(wn*32+jt*16+lr)*32 + lq*8];
    #pragma unroll
    for(int it=0;it<4;it++)
      #pragma unroll
      for(int jt=0;jt<2;jt++)
        acc[it][jt] = __builtin_amdgcn_mfma_f32_16x16x32_bf16(af[it], bfr[jt], acc[it][jt], 0,0,0);
  }
  if(FUSEV && n0 >= 1536){
    // transposed V write: vtbuf[b*768 + (nc-1536)][token], 4 consecutive tokens/lane
    #pragma unroll
    for(int it=0;it<4;it++){
      int tok0 = m0 + wm*64 + it*16 + lq*4;      // global row of r=0
      #pragma unroll
      for(int jt=0;jt<2;jt++){
        int vrow = (n0 - 1536) + wn*32 + jt*16 + lr;
        ushort4 pk; unsigned short* pks = (unsigned short*)&pk;
        #pragma unroll
        for(int r=0;r<4;r++) pks[r] = f2bf(acc[it][jt][r]);
        int b0 = tok0/577, t0 = tok0 - b0*577;
        if(tok0 + 3 < M_ && t0 + 3 < 577){
          *(ushort4*)&vtbuf[(size_t)(b0*768 + vrow)*VTLD + t0] = pk;
        } else {
          #pragma unroll
          for(int r=0;r<4;r++){
            int tg = tok0 + r;
            if(tg < M_){
              int bb = tg/577, tt = tg - bb*577;
              vtbuf[(size_t)(bb*768 + vrow)*VTLD + tt] = pks[r];
            }
          }
        }
      }
    }
  } else {
    #pragma unroll
    for(int it=0;it<4;it++){
      #pragma unroll
      for(int r=0;r<4;r++){
        int row = m0 + wm*64 + it*16 + lq*4 + r;
        if(row < Mdim){
          #pragma unroll
          for(int jt=0;jt<2;jt++){
            int col = n0 + wn*32 + jt*16 + lr;
            float v = acc[it][jt][r];
            if constexpr (BF16OUT)
              ((unsigned short*)Cout)[(size_t)row*LDC_ + col] = f2bf(v);
            else
              ((float*)Cout)[(size_t)row*LDC_ + col] = v + bias[col];
          }
        }
      }
    }
  }
}

// ---------------- fused flash attention, max-free softmax, S^T formulation ----------------
__global__ __launch_bounds__(256,4) void k_attn(const unsigned short* __restrict__ qkv,
                                                const unsigned short* __restrict__ vtbuf,
                                                unsigned short* __restrict__ aout){
  __shared__ __align__(16) unsigned short Ks[64*64];
  __shared__ __align__(16) unsigned short Vt[64*64];
  __shared__ __align__(16) unsigned short Ptt[128*PTLD];
  __shared__ float Ls[4][2][16][4];
  const int blk = blockIdx.x;
  const int bh = blk % 192, qt = blk / 192;
  const int b = bh / 12, h = bh % 12;
  const int t = threadIdx.x, w = t>>6, l = t&63, lq = l>>4, lr = l&15;
  const size_t base = (size_t)(b*577)*2304 + h*64;
  const int q0 = qt*128;
  s16x8 bq[2][2];
  #pragma unroll
  for(int it=0;it<2;it++){
    int qrow = q0 + w*32 + it*16 + lr; if(qrow > 576) qrow = 576;
    #pragma unroll
    for(int ks=0;ks<2;ks++)
      bq[it][ks] = *(const s16x8*)&qkv[base + (size_t)qrow*2304 + ks*32 + lq*8];
  }
  const int srow = w*8 + (l>>3);
  const int cswz8 = (((l&7) ^ (l>>3)) << 3);
  unsigned short* ldsK = Ks + (size_t)w*512;
  unsigned short* ldsV = Vt + (size_t)w*512;
  const unsigned short* gVbase = vtbuf + (size_t)(bh*64)*VTLD + cswz8;

  f32x4 acc_o[2][4] = {};
  float lsum[2] = {0.f, 0.f};
  const float CEXP = 0.18033688011112043f;              // 0.125 * log2(e)

  for(int j0=0; j0<577; j0+=64){
    __syncthreads();
    #pragma unroll
    for(int i=0;i<2;i++){
      int krow = j0 + i*32 + srow; if(krow > 576) krow = 576;
      gld_lds16(qkv + base + 768 + (size_t)krow*2304 + cswz8, ldsK + i*2048);
      gld_lds16(gVbase + (size_t)(i*32 + srow)*VTLD + j0,     ldsV + i*2048);
    }
    __syncthreads();
    f32x4 accs[2][4] = {};
    #pragma unroll
    for(int ks=0;ks<2;ks++){
      s16x8 ak[4];
      #pragma unroll
      for(int jt=0;jt<4;jt++){
        int j = jt*16 + lr;
        ak[jt] = *(const s16x8*)&Ks[j*64 + (((4*ks+lq) ^ (j&7))<<3)];
      }
      #pragma unroll
      for(int it=0;it<2;it++)
        #pragma unroll
        for(int jt=0;jt<4;jt++)
          accs[it][jt] = __builtin_amdgcn_mfma_f32_16x16x32_bf16(ak[jt], bq[it][ks], accs[it][jt], 0,0,0);
    }
    #pragma unroll
    for(int it=0;it<2;it++){
      int qlocal = w*32 + it*16 + lr;
      #pragma unroll
      for(int jt=0;jt<4;jt++){
        ushort4 pk;
        unsigned short* pks = (unsigned short*)&pk;
        #pragma unroll
        for(int r=0;r<4;r++){
          int j = j0 + jt*16 + lq*4 + r;
          float p = exp2f(accs[it][jt][r] * CEXP);
          if(j > 576) p = 0.f;
          lsum[it] += p;
          pks[r] = f2bf(p);
        }
        *(ushort4*)&Ptt[qlocal*PTLD + jt*16 + lq*4] = pk;
      }
    }
    #pragma unroll
    for(int ks=0;ks<2;ks++){
      s16x8 ap[2], bv[4];
      #pragma unroll
      for(int it=0;it<2;it++)
        ap[it] = *(const s16x8*)&Ptt[(w*32+it*16+lr)*PTLD + ks*32 + lq*8];
      #pragma unroll
      for(int dt=0;dt<4;dt++){
        int d = dt*16 + lr;
        bv[dt] = *(const s16x8*)&Vt[d*64 + (((4*ks+lq) ^ (d&7))<<3)];
      }
      #pragma unroll
      for(int it=0;it<2;it++)
        #pragma unroll
        for(int dt=0;dt<4;dt++)
          acc_o[it][dt] = __builtin_amdgcn_mfma_f32_16x16x32_bf16(ap[it], bv[dt], acc_o[it][dt], 0,0,0);
    }
  }
  #pragma unroll
  for(int it=0;it<2;it++) Ls[w][it][lr][lq] = lsum[it];
  #pragma unroll
  for(int it=0;it<2;it++){
    #pragma unroll
    for(int r=0;r<4;r++){
      int n = q0 + w*32 + it*16 + lq*4 + r;
      if(n <= 576){
        int q16 = lq*4 + r;
        float lt = Ls[w][it][q16][0] + Ls[w][it][q16][1] + Ls[w][it][q16][2] + Ls[w][it][q16][3];
        float inv = 1.f / lt;
        #pragma unroll
        for(int dt=0;dt<4;dt++)
          aout[(size_t)(b*577+n)*768 + h*64 + dt*16 + lr] = f2bf(acc_o[it][dt][r]*inv);
      }
    }
  }
}

// ---------------- fp32 top-k path (exact ranking) ----------------
__global__ void k_qcls(const float* __restrict__ x, const float* __restrict__ Wqkv,
                       float* __restrict__ qcls){
  __shared__ float xs[768];
  __shared__ float part[4][64];
  const int b = blockIdx.y, j0 = blockIdx.x*64;
  const int t = threadIdx.x;
  const float* xr = x + (size_t)b*577*768;
  xs[t] = xr[t]; xs[t+256] = xr[t+256]; xs[t+512] = xr[t+512];
  __syncthreads();
  const int jl = t & 63, cs = t >> 6;
  float acc = 0.f;
  const float* wp = Wqkv + (size_t)(cs*192)*2304 + j0 + jl;
  #pragma unroll 4
  for(int c=0;c<192;c++){ acc += xs[cs*192+c] * wp[0]; wp += 2304; }
  part[cs][jl] = acc;
  __syncthreads();
  if(t < 64) qcls[b*768 + j0 + t] = part[0][t]+part[1][t]+part[2][t]+part[3][t];
}
__global__ void k_u(const float* __restrict__ Wqkv, const float* __restrict__ qcls,
                    float* __restrict__ u){
  int h = blockIdx.x, b = blockIdx.y, c = threadIdx.x;  // 768 threads
  const float* qc = qcls + b*768 + h*64;
  const float* wr = Wqkv + (size_t)c*2304 + 768 + h*64;
  float acc = 0.f;
  #pragma unroll
  for(int d=0;d<64;d++) acc += wr[d]*qc[d];
  u[(size_t)(b*12+h)*768 + c] = acc;
}
__global__ void k_attw(const float* __restrict__ x, const float* __restrict__ u,
                       float* __restrict__ attw){
  int blk = blockIdx.x;               // 16*577 blocks of 1 wave
  int b = blk/577, m = blk%577;
  int lane = threadIdx.x;
  const float* xr = x + (size_t)(b*577+m)*768;
  const float* ub = u + (size_t)b*12*768;
  float part[12];
  #pragma unroll
  for(int h=0;h<12;h++) part[h]=0.f;
  #pragma unroll
  for(int i=0;i<12;i++){
    float xv = xr[i*64 + lane];
    #pragma unroll
    for(int h=0;h<12;h++) part[h] += xv * ub[h*768 + i*64 + lane];
  }
  float s = 0.f;
  #pragma unroll
  for(int h=0;h<12;h++){
    float v = part[h];
    #pragma unroll
    for(int off=32; off; off>>=1) v += __shfl_xor(v, off);
    s += fabsf(v);
  }
  if(lane==0) attw[b*577 + m] = 0.125f * s;
}
__global__ void k_topk(const float* __restrict__ attw, int* __restrict__ idxbuf){
  __shared__ float sw[576];
  __shared__ int wtot[9];
  int b = blockIdx.x, t = threadIdx.x;     // 576 threads
  float wv = attw[b*577 + 1 + t];
  sw[t] = wv;
  __syncthreads();
  int rank = 0;
  for(int j=0;j<576;j++){
    float wj = sw[j];
    rank += (wj > wv) || (wj == wv && j < t);
  }
  bool kept = rank < NKEEP;
  unsigned long long mask = __ballot(kept);
  int wid = t>>6, lane = t&63;
  int pos = __popcll(mask & ((1ull<<lane)-1ull));
  if(lane==0) wtot[wid] = __popcll(mask);
  __syncthreads();
  int off0 = 0;
  for(int q=0;q<wid;q++) off0 += wtot[q];
  if(kept) idxbuf[b*KROWS + 1 + off0 + pos] = t+1;
  if(t==0) idxbuf[b*KROWS] = 0;
}
__global__ void k_fill_keep(const int* __restrict__ idxbuf, float* __restrict__ out2){
  int i4 = blockIdx.x*256 + threadIdx.x;
  float v = (float)idxbuf[i4/192];
  ((float4*)out2)[i4] = make_float4(v,v,v,v);
}

extern "C" void kernel_launch(void* const* d_in, const int* in_sizes, int n_in,
                              void* d_out, int out_size, void* d_ws, size_t ws_size,
                              hipStream_t stream){
  const float* x     = (const float*)d_in[0];
  const float* Wqkv  = (const float*)d_in[1];
  const float* Wproj = (const float*)d_in[2];
  const float* bias  = (const float*)d_in[3];
  float* out  = (float*)d_out;
  float* out2 = out + (size_t)M_*768;      // keep_index chunk (float32)

  char* ws = (char*)d_ws;
  size_t off = 0;
  auto alloc = [&](size_t bytes)->void*{ void* p = ws + off; off += (bytes + 255) & ~(size_t)255; return p; };
  unsigned short* xb     = (unsigned short*)alloc((size_t)M_*768*2);
  unsigned short* wqkvT  = (unsigned short*)alloc((size_t)QKVN*768*2);
  unsigned short* wprojT = (unsigned short*)alloc((size_t)768*768*2);
  unsigned short* qkvb   = (unsigned short*)alloc((size_t)M_*QKVN*2);
  unsigned short* aoutb  = (unsigned short*)alloc((size_t)M_*768*2);
  unsigned short* vtbuf  = (unsigned short*)alloc((size_t)192*64*VTLD*2);
  float* qcls   = (float*)alloc((size_t)16*768*4);
  float* u      = (float*)alloc((size_t)16*12*768*4);
  float* attw   = (float*)alloc((size_t)16*577*4);
  int*   idxbuf = (int*)alloc((size_t)16*KROWS*4);

  // bf16 casts / transposes
  k_cvt_x<<<6924, 256, 0, stream>>>(x, xb);
  k_transpose_cvt<<<dim3(36,12), 256, 0, stream>>>(Wqkv,  wqkvT, 768, 2304);
  k_transpose_cvt<<<dim3(12,12), 256, 0, stream>>>(Wproj, wprojT, 768, 768);
  // QKV GEMM (bf16 out; V-tiles written transposed into vtbuf). 128x64 tiles.
  k_gemm_bt<QKVN, true, true, 36><<<73*36, 256, 0, stream>>>(xb, wqkvT, qkvb, nullptr, M_, vtbuf);
  // fp32 top-k weight path
  k_qcls<<<dim3(12,16), 256, 0, stream>>>(x, Wqkv, qcls);
  k_u<<<dim3(12,16), 768, 0, stream>>>(Wqkv, qcls, u);
  k_attw<<<16*577, 64, 0, stream>>>(x, u, attw);
  k_topk<<<16, 576, 0, stream>>>(attw, idxbuf);
  k_fill_keep<<<(16*KROWS*768/4 + 255)/256, 256, 0, stream>>>(idxbuf, out2);
  // attention + out-proj
  k_attn<<<960, 256, 0, stream>>>(qkvb, vtbuf, aoutb);
  k_gemm_bt<768, false, false, 12><<<73*12, 256, 0, stream>>>(aoutb, wprojT, out, bias, M_, nullptr);
}

// Round 8
// 282.510 us; speedup vs baseline: 1.0544x; 1.0544x over previous
//
#include <hip/hip_runtime.h>
#include <hip/hip_bf16.h>
#include <stdint.h>

// Problem constants
#define B_    16
#define N_    577
#define C_    768
#define H_    12
#define M_    (B_*N_)     // 9232 rows
#define QKVN  (3*C_)      // 2304
#define NKEEP 403         // int(576*0.7)
#define KROWS (NKEEP+1)   // 404
#define VTLD  640         // vtbuf padded row length
#define PTLD  72          // Ptt row stride (ushorts)

typedef short s16x8 __attribute__((ext_vector_type(8)));
typedef float f32x4 __attribute__((ext_vector_type(4)));

__device__ __forceinline__ unsigned short f2bf(float x){
  unsigned int u = __float_as_uint(x);
  u += 0x7FFF + ((u >> 16) & 1);          // round-to-nearest-even
  return (unsigned short)(u >> 16);
}

// async global->LDS, 16B per lane; lds dest = wave-uniform base + lane*16
__device__ __forceinline__ void gld_lds16(const void* g, void* l){
  __builtin_amdgcn_global_load_lds(
      (const __attribute__((address_space(1))) unsigned int*)g,
      (__attribute__((address_space(3))) unsigned int*)l, 16, 0, 0);
}

// Generic XCD-panel tile mapping: xcd = L&7 owns m-panel [x*M9, x*M9+M9);
// tail m-tiles (>= 8*M9) distributed to match round-robin per-XCD counts (bijective).
template<int NT, int M9, int MTILES>
__device__ __forceinline__ void tile_map(int L, int& mt, int& nt){
  constexpr int NB = MTILES*NT;
  int x = L & 7, j = L >> 3;
  if(j < M9*NT){
    nt = j/M9; mt = x*M9 + (j - nt*M9);    // n-outer: M9 consecutive blocks share B-tile
  } else {
    int offt = 0;
    #pragma unroll
    for(int y=0;y<8;y++) if(y<x) offt += ((NB-1-y)>>3) + 1 - M9*NT;  // tail_y
    int ft = offt + (j - M9*NT);
    mt = 8*M9 + ft/NT;
    nt = ft - (ft/NT)*NT;
  }
}

// ---------------- cast x -> bf16 (vectorized) ----------------
__global__ void k_cvt_x(const float* __restrict__ x, unsigned short* __restrict__ xb){
  int i = blockIdx.x*256 + threadIdx.x;
  float4 v = ((const float4*)x)[i];
  ushort4 o; o.x=f2bf(v.x); o.y=f2bf(v.y); o.z=f2bf(v.z); o.w=f2bf(v.w);
  ((ushort4*)xb)[i] = o;
}

// ------------- transpose+cast weights: out[c][r] = bf16(in[r][c]) -------------
__global__ void k_transpose_cvt(const float* __restrict__ in, unsigned short* __restrict__ out,
                                int R, int CC){
  __shared__ float tile[64][65];
  int r0 = blockIdx.y*64, c0 = blockIdx.x*64;
  int tx = threadIdx.x & 63, ty = threadIdx.x >> 6;
  #pragma unroll
  for(int i=0;i<16;i++){
    int r = ty + i*4;
    tile[r][tx] = in[(size_t)(r0+r)*CC + c0 + tx];
  }
  __syncthreads();
  #pragma unroll
  for(int i=0;i<16;i++){
    int c = ty + i*4;
    out[(size_t)(c0+c)*R + r0 + tx] = f2bf(tile[tx][c]);
  }
}

// ---------------- bf16 MFMA GEMM, 128x128 tile (round-5 form, best known) ----------------
// FUSEV: n-tiles >= 1536 write transposed V into vtbuf instead of Cout.
template<int LDC_, bool BF16OUT, bool FUSEV, int NT>
__global__ __launch_bounds__(256) void k_gemm_bt(const unsigned short* __restrict__ A,
                          const unsigned short* __restrict__ Bt,
                          void* __restrict__ Cout,
                          const float* __restrict__ bias, int Mdim,
                          unsigned short* __restrict__ vtbuf){
  __shared__ __align__(16) unsigned short As[128*32];
  __shared__ __align__(16) unsigned short Bs[128*32];
  const int t = threadIdx.x;
  const int w = t>>6, l = t&63, lq = l>>4, lr = l&15;
  const int wm = w>>1, wn = w&1;
  int mt, nt; tile_map<NT, 9, 73>(blockIdx.x, mt, nt);
  const int m0 = mt*128, n0 = nt*128;
  int rA0 = m0 + (t>>2);       if(rA0 >= Mdim) rA0 = Mdim-1;
  int rA1 = m0 + ((t+256)>>2); if(rA1 >= Mdim) rA1 = Mdim-1;
  const unsigned short* gA0 = A  + (size_t)rA0*768 + (t&3)*8;
  const unsigned short* gA1 = A  + (size_t)rA1*768 + (t&3)*8;
  const unsigned short* gB0 = Bt + (size_t)(n0 + (t>>2))*768 + (t&3)*8;
  const unsigned short* gB1 = Bt + (size_t)(n0 + ((t+256)>>2))*768 + (t&3)*8;
  unsigned short* lA0 = As + (size_t)w*512;
  unsigned short* lA1 = As + 2048 + (size_t)w*512;
  unsigned short* lB0 = Bs + (size_t)w*512;
  unsigned short* lB1 = Bs + 2048 + (size_t)w*512;
  f32x4 acc[4][4] = {};
  for(int kt=0; kt<24; ++kt){
    const int ko = kt*32;
    __syncthreads();
    gld_lds16(gA0 + ko, lA0); gld_lds16(gA1 + ko, lA1);
    gld_lds16(gB0 + ko, lB0); gld_lds16(gB1 + ko, lB1);
    __syncthreads();
    s16x8 af[4], bfr[4];
    #pragma unroll
    for(int it=0;it<4;it++) af[it]  = *(const s16x8*)&As[(wm*64+it*16+lr)*32 + lq*8];
    #pragma unroll
    for(int jt=0;jt<4;jt++) bfr[jt] = *(const s16x8*)&Bs[(wn*64+jt*16+lr)*32 + lq*8];
    #pragma unroll
    for(int it=0;it<4;it++)
      #pragma unroll
      for(int jt=0;jt<4;jt++)
        acc[it][jt] = __builtin_amdgcn_mfma_f32_16x16x32_bf16(af[it], bfr[jt], acc[it][jt], 0,0,0);
  }
  if(FUSEV && n0 >= 1536){
    // transposed V write: vtbuf[b*768 + (nc-1536)][token], 4 consecutive tokens/lane
    #pragma unroll
    for(int it=0;it<4;it++){
      int tok0 = m0 + wm*64 + it*16 + lq*4;      // global row of r=0
      #pragma unroll
      for(int jt=0;jt<4;jt++){
        int vrow = (n0 - 1536) + wn*64 + jt*16 + lr;
        ushort4 pk; unsigned short* pks = (unsigned short*)&pk;
        #pragma unroll
        for(int r=0;r<4;r++) pks[r] = f2bf(acc[it][jt][r]);
        int b0 = tok0/577, t0 = tok0 - b0*577;
        if(tok0 + 3 < M_ && t0 + 3 < 577){
          *(ushort4*)&vtbuf[(size_t)(b0*768 + vrow)*VTLD + t0] = pk;
        } else {
          #pragma unroll
          for(int r=0;r<4;r++){
            int tg = tok0 + r;
            if(tg < M_){
              int bb = tg/577, tt = tg - bb*577;
              vtbuf[(size_t)(bb*768 + vrow)*VTLD + tt] = pks[r];
            }
          }
        }
      }
    }
  } else {
    #pragma unroll
    for(int it=0;it<4;it++){
      #pragma unroll
      for(int r=0;r<4;r++){
        int row = m0 + wm*64 + it*16 + lq*4 + r;
        if(row < Mdim){
          #pragma unroll
          for(int jt=0;jt<4;jt++){
            int col = n0 + wn*64 + jt*16 + lr;
            float v = acc[it][jt][r];
            if constexpr (BF16OUT)
              ((unsigned short*)Cout)[(size_t)row*LDC_ + col] = f2bf(v);
            else
              ((float*)Cout)[(size_t)row*LDC_ + col] = v + bias[col];
          }
        }
      }
    }
  }
}

// ---------------- bf16 MFMA GEMM, 64x128 tile (for parallelism-starved GEMM2) ----------------
// wave-tile 32x64 (acc 2x4 = 32 AGPR). f32 out + bias.
__global__ __launch_bounds__(256) void k_gemm_bt64(const unsigned short* __restrict__ A,
                          const unsigned short* __restrict__ Bt,
                          float* __restrict__ Cout,
                          const float* __restrict__ bias, int Mdim){
  __shared__ __align__(16) unsigned short As[64*32];    // 4 KB
  __shared__ __align__(16) unsigned short Bs[128*32];   // 8 KB
  const int t = threadIdx.x;
  const int w = t>>6, l = t&63, lq = l>>4, lr = l&15;
  const int wm = w>>1, wn = w&1;                        // wave-tile rows wm*32, cols wn*64
  int mt, nt; tile_map<6, 18, 145>(blockIdx.x, mt, nt);
  const int m0 = mt*64, n0 = nt*128;
  int rA0 = m0 + (t>>2);       if(rA0 >= Mdim) rA0 = Mdim-1;
  const unsigned short* gA0 = A  + (size_t)rA0*768 + (t&3)*8;
  const unsigned short* gB0 = Bt + (size_t)(n0 + (t>>2))*768 + (t&3)*8;
  const unsigned short* gB1 = Bt + (size_t)(n0 + ((t+256)>>2))*768 + (t&3)*8;
  unsigned short* lA0 = As + (size_t)w*512;
  unsigned short* lB0 = Bs + (size_t)w*512;
  unsigned short* lB1 = Bs + 2048 + (size_t)w*512;
  f32x4 acc[2][4] = {};
  for(int kt=0; kt<24; ++kt){
    const int ko = kt*32;
    __syncthreads();
    gld_lds16(gA0 + ko, lA0);
    gld_lds16(gB0 + ko, lB0); gld_lds16(gB1 + ko, lB1);
    __syncthreads();
    s16x8 af[2], bfr[4];
    #pragma unroll
    for(int it=0;it<2;it++) af[it]  = *(const s16x8*)&As[(wm*32+it*16+lr)*32 + lq*8];
    #pragma unroll
    for(int jt=0;jt<4;jt++) bfr[jt] = *(const s16x8*)&Bs[(wn*64+jt*16+lr)*32 + lq*8];
    #pragma unroll
    for(int it=0;it<2;it++)
      #pragma unroll
      for(int jt=0;jt<4;jt++)
        acc[it][jt] = __builtin_amdgcn_mfma_f32_16x16x32_bf16(af[it], bfr[jt], acc[it][jt], 0,0,0);
  }
  #pragma unroll
  for(int it=0;it<2;it++){
    #pragma unroll
    for(int r=0;r<4;r++){
      int row = m0 + wm*32 + it*16 + lq*4 + r;
      if(row < Mdim){
        #pragma unroll
        for(int jt=0;jt<4;jt++){
          int col = n0 + wn*64 + jt*16 + lr;
          Cout[(size_t)row*768 + col] = acc[it][jt][r] + bias[col];
        }
      }
    }
  }
}

// ---------------- fused flash attention, max-free softmax, S^T, peeled edge tile ----------------
__global__ __launch_bounds__(256,4) void k_attn(const unsigned short* __restrict__ qkv,
                                                const unsigned short* __restrict__ vtbuf,
                                                unsigned short* __restrict__ aout){
  __shared__ __align__(16) unsigned short Ks[64*64];
  __shared__ __align__(16) unsigned short Vt[64*64];
  __shared__ __align__(16) unsigned short Ptt[128*PTLD];
  __shared__ float Ls[4][2][16][4];
  const int blk = blockIdx.x;
  const int bh = blk % 192, qt = blk / 192;
  const int b = bh / 12, h = bh % 12;
  const int t = threadIdx.x, w = t>>6, l = t&63, lq = l>>4, lr = l&15;
  const size_t base = (size_t)(b*577)*2304 + h*64;
  const int q0 = qt*128;
  s16x8 bq[2][2];
  #pragma unroll
  for(int it=0;it<2;it++){
    int qrow = q0 + w*32 + it*16 + lr; if(qrow > 576) qrow = 576;
    #pragma unroll
    for(int ks=0;ks<2;ks++)
      bq[it][ks] = *(const s16x8*)&qkv[base + (size_t)qrow*2304 + ks*32 + lq*8];
  }
  const int srow = w*8 + (l>>3);
  const int cswz8 = (((l&7) ^ (l>>3)) << 3);
  unsigned short* ldsK = Ks + (size_t)w*512;
  unsigned short* ldsV = Vt + (size_t)w*512;
  const unsigned short* gVbase = vtbuf + (size_t)(bh*64)*VTLD + cswz8;

  f32x4 acc_o[2][4] = {};
  float lsum[2] = {0.f, 0.f};
  const float CEXP = 0.18033688011112043f;              // 0.125 * log2(e)

  auto tile_body = [&](int j0, bool edge){
    __syncthreads();
    #pragma unroll
    for(int i=0;i<2;i++){
      int krow = j0 + i*32 + srow; if(krow > 576) krow = 576;
      gld_lds16(qkv + base + 768 + (size_t)krow*2304 + cswz8, ldsK + i*2048);
      gld_lds16(gVbase + (size_t)(i*32 + srow)*VTLD + j0,     ldsV + i*2048);
    }
    __syncthreads();
    f32x4 accs[2][4] = {};
    #pragma unroll
    for(int ks=0;ks<2;ks++){
      s16x8 ak[4];
      #pragma unroll
      for(int jt=0;jt<4;jt++){
        int j = jt*16 + lr;
        ak[jt] = *(const s16x8*)&Ks[j*64 + (((4*ks+lq) ^ (j&7))<<3)];
      }
      #pragma unroll
      for(int it=0;it<2;it++)
        #pragma unroll
        for(int jt=0;jt<4;jt++)
          accs[it][jt] = __builtin_amdgcn_mfma_f32_16x16x32_bf16(ak[jt], bq[it][ks], accs[it][jt], 0,0,0);
    }
    #pragma unroll
    for(int it=0;it<2;it++){
      int qlocal = w*32 + it*16 + lr;
      #pragma unroll
      for(int jt=0;jt<4;jt++){
        ushort4 pk;
        unsigned short* pks = (unsigned short*)&pk;
        #pragma unroll
        for(int r=0;r<4;r++){
          float p = exp2f(accs[it][jt][r] * CEXP);
          if(edge){ if(j0 + jt*16 + lq*4 + r > 576) p = 0.f; }
          lsum[it] += p;
          pks[r] = f2bf(p);
        }
        *(ushort4*)&Ptt[qlocal*PTLD + jt*16 + lq*4] = pk;
      }
    }
    #pragma unroll
    for(int ks=0;ks<2;ks++){
      s16x8 ap[2], bv[4];
      #pragma unroll
      for(int it=0;it<2;it++)
        ap[it] = *(const s16x8*)&Ptt[(w*32+it*16+lr)*PTLD + ks*32 + lq*8];
      #pragma unroll
      for(int dt=0;dt<4;dt++){
        int d = dt*16 + lr;
        bv[dt] = *(const s16x8*)&Vt[d*64 + (((4*ks+lq) ^ (d&7))<<3)];
      }
      #pragma unroll
      for(int it=0;it<2;it++)
        #pragma unroll
        for(int dt=0;dt<4;dt++)
          acc_o[it][dt] = __builtin_amdgcn_mfma_f32_16x16x32_bf16(ap[it], bv[dt], acc_o[it][dt], 0,0,0);
    }
  };
  for(int j0=0; j0<576; j0+=64) tile_body(j0, false);   // j <= 575: no masking needed
  tile_body(576, true);                                 // edge tile: only j=576 valid

  #pragma unroll
  for(int it=0;it<2;it++) Ls[w][it][lr][lq] = lsum[it];
  #pragma unroll
  for(int it=0;it<2;it++){
    #pragma unroll
    for(int r=0;r<4;r++){
      int n = q0 + w*32 + it*16 + lq*4 + r;
      if(n <= 576){
        int q16 = lq*4 + r;
        float lt = Ls[w][it][q16][0] + Ls[w][it][q16][1] + Ls[w][it][q16][2] + Ls[w][it][q16][3];
        float inv = 1.f / lt;
        #pragma unroll
        for(int dt=0;dt<4;dt++)
          aout[(size_t)(b*577+n)*768 + h*64 + dt*16 + lr] = f2bf(acc_o[it][dt][r]*inv);
      }
    }
  }
}

// ---------------- fp32 top-k path (exact ranking) ----------------
__global__ void k_qcls(const float* __restrict__ x, const float* __restrict__ Wqkv,
                       float* __restrict__ qcls){
  __shared__ float xs[768];
  __shared__ float part[4][64];
  const int b = blockIdx.y, j0 = blockIdx.x*64;
  const int t = threadIdx.x;
  const float* xr = x + (size_t)b*577*768;
  xs[t] = xr[t]; xs[t+256] = xr[t+256]; xs[t+512] = xr[t+512];
  __syncthreads();
  const int jl = t & 63, cs = t >> 6;
  float acc = 0.f;
  const float* wp = Wqkv + (size_t)(cs*192)*2304 + j0 + jl;
  #pragma unroll 4
  for(int c=0;c<192;c++){ acc += xs[cs*192+c] * wp[0]; wp += 2304; }
  part[cs][jl] = acc;
  __syncthreads();
  if(t < 64) qcls[b*768 + j0 + t] = part[0][t]+part[1][t]+part[2][t]+part[3][t];
}
__global__ void k_u(const float* __restrict__ Wqkv, const float* __restrict__ qcls,
                    float* __restrict__ u){
  int h = blockIdx.x, b = blockIdx.y, c = threadIdx.x;  // 768 threads
  const float* qc = qcls + b*768 + h*64;
  const float* wr = Wqkv + (size_t)c*2304 + 768 + h*64;
  float acc = 0.f;
  #pragma unroll
  for(int d=0;d<64;d++) acc += wr[d]*qc[d];
  u[(size_t)(b*12+h)*768 + c] = acc;
}
__global__ void k_attw(const float* __restrict__ x, const float* __restrict__ u,
                       float* __restrict__ attw){
  int blk = blockIdx.x;               // 16*577 blocks of 1 wave
  int b = blk/577, m = blk%577;
  int lane = threadIdx.x;
  const float* xr = x + (size_t)(b*577+m)*768;
  const float* ub = u + (size_t)b*12*768;
  float part[12];
  #pragma unroll
  for(int h=0;h<12;h++) part[h]=0.f;
  #pragma unroll
  for(int i=0;i<12;i++){
    float xv = xr[i*64 + lane];
    #pragma unroll
    for(int h=0;h<12;h++) part[h] += xv * ub[h*768 + i*64 + lane];
  }
  float s = 0.f;
  #pragma unroll
  for(int h=0;h<12;h++){
    float v = part[h];
    #pragma unroll
    for(int off=32; off; off>>=1) v += __shfl_xor(v, off);
    s += fabsf(v);
  }
  if(lane==0) attw[b*577 + m] = 0.125f * s;
}
__global__ void k_topk(const float* __restrict__ attw, int* __restrict__ idxbuf){
  __shared__ float sw[576];
  __shared__ int wtot[9];
  int b = blockIdx.x, t = threadIdx.x;     // 576 threads
  float wv = attw[b*577 + 1 + t];
  sw[t] = wv;
  __syncthreads();
  int rank = 0;
  for(int j=0;j<576;j++){
    float wj = sw[j];
    rank += (wj > wv) || (wj == wv && j < t);
  }
  bool kept = rank < NKEEP;
  unsigned long long mask = __ballot(kept);
  int wid = t>>6, lane = t&63;
  int pos = __popcll(mask & ((1ull<<lane)-1ull));
  if(lane==0) wtot[wid] = __popcll(mask);
  __syncthreads();
  int off0 = 0;
  for(int q=0;q<wid;q++) off0 += wtot[q];
  if(kept) idxbuf[b*KROWS + 1 + off0 + pos] = t+1;
  if(t==0) idxbuf[b*KROWS] = 0;
}
__global__ void k_fill_keep(const int* __restrict__ idxbuf, float* __restrict__ out2){
  int i4 = blockIdx.x*256 + threadIdx.x;
  float v = (float)idxbuf[i4/192];
  ((float4*)out2)[i4] = make_float4(v,v,v,v);
}

extern "C" void kernel_launch(void* const* d_in, const int* in_sizes, int n_in,
                              void* d_out, int out_size, void* d_ws, size_t ws_size,
                              hipStream_t stream){
  const float* x     = (const float*)d_in[0];
  const float* Wqkv  = (const float*)d_in[1];
  const float* Wproj = (const float*)d_in[2];
  const float* bias  = (const float*)d_in[3];
  float* out  = (float*)d_out;
  float* out2 = out + (size_t)M_*768;      // keep_index chunk (float32)

  char* ws = (char*)d_ws;
  size_t off = 0;
  auto alloc = [&](size_t bytes)->void*{ void* p = ws + off; off += (bytes + 255) & ~(size_t)255; return p; };
  unsigned short* xb     = (unsigned short*)alloc((size_t)M_*768*2);
  unsigned short* wqkvT  = (unsigned short*)alloc((size_t)QKVN*768*2);
  unsigned short* wprojT = (unsigned short*)alloc((size_t)768*768*2);
  unsigned short* qkvb   = (unsigned short*)alloc((size_t)M_*QKVN*2);
  unsigned short* aoutb  = (unsigned short*)alloc((size_t)M_*768*2);
  unsigned short* vtbuf  = (unsigned short*)alloc((size_t)192*64*VTLD*2);
  float* qcls   = (float*)alloc((size_t)16*768*4);
  float* u      = (float*)alloc((size_t)16*12*768*4);
  float* attw   = (float*)alloc((size_t)16*577*4);
  int*   idxbuf = (int*)alloc((size_t)16*KROWS*4);

  // bf16 casts / transposes
  k_cvt_x<<<6924, 256, 0, stream>>>(x, xb);
  k_transpose_cvt<<<dim3(36,12), 256, 0, stream>>>(Wqkv,  wqkvT, 768, 2304);
  k_transpose_cvt<<<dim3(12,12), 256, 0, stream>>>(Wproj, wprojT, 768, 768);
  // QKV GEMM (bf16 out; V-tiles written transposed into vtbuf). 128x128 tiles (R5 form).
  k_gemm_bt<QKVN, true, true, 18><<<73*18, 256, 0, stream>>>(xb, wqkvT, qkvb, nullptr, M_, vtbuf);
  // fp32 top-k weight path
  k_qcls<<<dim3(12,16), 256, 0, stream>>>(x, Wqkv, qcls);
  k_u<<<dim3(12,16), 768, 0, stream>>>(Wqkv, qcls, u);
  k_attw<<<16*577, 64, 0, stream>>>(x, u, attw);
  k_topk<<<16, 576, 0, stream>>>(attw, idxbuf);
  k_fill_keep<<<(16*KROWS*768/4 + 255)/256, 256, 0, stream>>>(idxbuf, out2);
  // attention + out-proj (64x128 tiles: 870 blocks vs 438)
  k_attn<<<960, 256, 0, stream>>>(qkvb, vtbuf, aoutb);
  k_gemm_bt64<<<145*6, 256, 0, stream>>>(aoutb, wprojT, out, bias, M_);
}